// Round 1
// baseline (1416.700 us; speedup 1.0000x reference)
//
#include <hip/hip_runtime.h>

// Problem constants
#define NND 8192   // nodes
#define FD  32     // feature dim
#define ED  32     // embedding dim
#define SUP 4      // relations
#define NB  2      // bases

#define TM  64     // K-tile
#define TMP 68     // padded A row stride in LDS (68 % 32 = 4 -> 8 rows span distinct banks)
#define KSPLIT 8   // k-chunks (each 4096 k, aligned within one relation s)

// --------------------------------------------------------------------------
// Kernel 1: build Veff (in LDS), G[s][m][e] into ws, and zero d_out.
// Veff[s][f][e] = sum_b W_comp[f%4][b] * W[b][s*8 + f/4][e]   (index-mismatch
// of the original reshape folded in here).
// G[s][m][e]  = sum_f features[m][f] * Veff[s][f][e]
// --------------------------------------------------------------------------
__global__ __launch_bounds__(256) void prep_g(
        const float* __restrict__ features,
        const float* __restrict__ W,
        const float* __restrict__ Wc,
        float* __restrict__ G,
        float* __restrict__ out) {
    __shared__ __align__(16) float Vlds[SUP * FD * ED];  // 4096 floats = 16 KB
    const int t = threadIdx.x;

    // Each block redundantly computes Veff (cheap: 8192 FMA)
    for (int i = t; i < SUP * FD * ED; i += 256) {
        const int e  = i & 31;
        const int f  = (i >> 5) & 31;
        const int s  = i >> 10;
        const int f2 = s * 8 + (f >> 2);  // row of V3
        const int s2 = f & 3;             // col-of-S of V3
        float v = 0.f;
        #pragma unroll
        for (int b = 0; b < NB; ++b)
            v += Wc[s2 * NB + b] * W[(b * FD + f2) * ED + e];
        Vlds[i] = v;
    }
    __syncthreads();

    const int gid = blockIdx.x * 256 + t;       // grid = 1024 blocks -> 262144 threads
    if (gid < NND * ED) out[gid] = 0.f;         // zero accumulator target

    const float4* feat4 = (const float4*)features;
    #pragma unroll
    for (int i = 0; i < 4; ++i) {
        const int o = gid + i * (1024 * 256);   // 4 outputs/thread -> 1,048,576
        const int e = o & 31;
        const int m = (o >> 5) & (NND - 1);
        const int s = o >> 18;                  // o / (32*8192)
        float acc = 0.f;
        #pragma unroll
        for (int f4 = 0; f4 < 8; ++f4) {
            const float4 fv = feat4[m * 8 + f4];
            acc += fv.x * Vlds[s * 1024 + (f4 * 4 + 0) * 32 + e];
            acc += fv.y * Vlds[s * 1024 + (f4 * 4 + 1) * 32 + e];
            acc += fv.z * Vlds[s * 1024 + (f4 * 4 + 2) * 32 + e];
            acc += fv.w * Vlds[s * 1024 + (f4 * 4 + 3) * 32 + e];
        }
        G[o] = acc;
    }
}

// --------------------------------------------------------------------------
// Kernel 2: out[n][e] += sum_{m in chunk} A[s][n][m] * G[s][m][e]
// Block: 256 threads, owns 128 rows x 32 e; 64 n-blocks x 8 k-chunks.
// Thread: 4 rows (r, r+32, r+64, r+96) x 4 e (eg*4..eg*4+3).
// --------------------------------------------------------------------------
#define FMA4(acc, sa, g) { acc.x += (sa) * (g).x; acc.y += (sa) * (g).y; \
                           acc.z += (sa) * (g).z; acc.w += (sa) * (g).w; }

__global__ __launch_bounds__(256) void rgcn_main(
        const float* __restrict__ A,
        const float* __restrict__ G,
        float* __restrict__ out) {
    __shared__ __align__(16) float Asb[128 * TMP];  // 34816 B
    __shared__ __align__(16) float Gsb[TM * 32];    // 8192 B

    const int t  = threadIdx.x;
    const int bx = blockIdx.x;          // 512 blocks
    const int nb = bx & 63;             // 64 n-blocks
    const int kb = bx >> 6;             // 8 k-chunks
    const int s       = kb >> 1;        // relation (chunk stays inside one s)
    const int m_start = (kb & 1) * 4096;
    const int n0      = nb * 128;

    const float* Abase = A + ((size_t)s * NND + n0) * NND;  // + row*8192 + m
    const float* Gbase = G + (size_t)s * NND * 32;

    const int eg = t & 7;               // e-group: e = eg*4 .. eg*4+3
    const int r  = t >> 3;              // base row 0..31

    float4 acc0 = {0.f, 0.f, 0.f, 0.f};
    float4 acc1 = acc0, acc2 = acc0, acc3 = acc0;

    for (int step = 0; step < 4096 / TM; ++step) {
        const int m0 = m_start + step * TM;
        __syncthreads();
        // Stage A tile: 128 rows x 64 floats (2048 float4 stores)
        #pragma unroll
        for (int it = 0; it < 8; ++it) {
            const int q   = it * 256 + t;
            const int row = q >> 4;
            const int c4  = q & 15;
            const float4 v = *(const float4*)(Abase + (size_t)row * NND + m0 + c4 * 4);
            *(float4*)&Asb[row * TMP + c4 * 4] = v;
        }
        // Stage G tile: 64 x 32 contiguous (512 float4)
        const float4* gsrc = (const float4*)(Gbase + (size_t)m0 * 32);
        #pragma unroll
        for (int it = 0; it < 2; ++it) {
            const int q = it * 256 + t;
            ((float4*)Gsb)[q] = gsrc[q];
        }
        __syncthreads();

        #pragma unroll
        for (int k4 = 0; k4 < TM; k4 += 4) {
            const float4 a0 = *(const float4*)&Asb[(r +  0) * TMP + k4];
            const float4 a1 = *(const float4*)&Asb[(r + 32) * TMP + k4];
            const float4 a2 = *(const float4*)&Asb[(r + 64) * TMP + k4];
            const float4 a3 = *(const float4*)&Asb[(r + 96) * TMP + k4];
            const float4 g0 = *(const float4*)&Gsb[(k4 + 0) * 32 + eg * 4];
            const float4 g1 = *(const float4*)&Gsb[(k4 + 1) * 32 + eg * 4];
            const float4 g2 = *(const float4*)&Gsb[(k4 + 2) * 32 + eg * 4];
            const float4 g3 = *(const float4*)&Gsb[(k4 + 3) * 32 + eg * 4];

            FMA4(acc0, a0.x, g0); FMA4(acc0, a0.y, g1); FMA4(acc0, a0.z, g2); FMA4(acc0, a0.w, g3);
            FMA4(acc1, a1.x, g0); FMA4(acc1, a1.y, g1); FMA4(acc1, a1.z, g2); FMA4(acc1, a1.w, g3);
            FMA4(acc2, a2.x, g0); FMA4(acc2, a2.y, g1); FMA4(acc2, a2.z, g2); FMA4(acc2, a2.w, g3);
            FMA4(acc3, a3.x, g0); FMA4(acc3, a3.y, g1); FMA4(acc3, a3.z, g2); FMA4(acc3, a3.w, g3);
        }
    }

    // Epilogue: split-K accumulate into out (8 contributions per element total)
    #pragma unroll
    for (int j = 0; j < 4; ++j) {
        const float4 a = (j == 0) ? acc0 : (j == 1) ? acc1 : (j == 2) ? acc2 : acc3;
        float* p = out + (size_t)(n0 + r + 32 * j) * 32 + eg * 4;
        atomicAdd(p + 0, a.x);
        atomicAdd(p + 1, a.y);
        atomicAdd(p + 2, a.z);
        atomicAdd(p + 3, a.w);
    }
}

extern "C" void kernel_launch(void* const* d_in, const int* in_sizes, int n_in,
                              void* d_out, int out_size, void* d_ws, size_t ws_size,
                              hipStream_t stream) {
    const float* features = (const float*)d_in[0];
    const float* A        = (const float*)d_in[1];
    const float* W        = (const float*)d_in[2];
    const float* Wc       = (const float*)d_in[3];
    float* out = (float*)d_out;
    float* G   = (float*)d_ws;   // 4*8192*32 floats = 4 MB

    prep_g<<<1024, 256, 0, stream>>>(features, W, Wc, G, out);
    rgcn_main<<<64 * KSPLIT, 256, 0, stream>>>(A, G, out);
}